// Round 5
// baseline (1180.709 us; speedup 1.0000x reference)
//
#include <hip/hip_runtime.h>

#define NNODES 20000
#define EEDGES 320000
#define DD     256
#define NEG_SLOPE 0.2f
#define SCAN_BLOCKS ((NNODES + 255) / 256)

// ---------------- CSR build ----------------

__global__ void zero_ints_k(int* __restrict__ p, int n) {
    int i = blockIdx.x * 256 + threadIdx.x;
    if (i < n) p[i] = 0;
}

__global__ void hist_k(const int* __restrict__ dst, int* __restrict__ rowptr) {
    int i = blockIdx.x * 256 + threadIdx.x;
    if (i < EEDGES) atomicAdd(&rowptr[dst[i] + 1], 1);
}

__global__ __launch_bounds__(256) void scan1_k(int* __restrict__ rowptr, int* __restrict__ bsums) {
    __shared__ int buf[256];
    int idx = blockIdx.x * 256 + threadIdx.x;
    int v = (idx < NNODES) ? rowptr[idx + 1] : 0;
    buf[threadIdx.x] = v;
    __syncthreads();
#pragma unroll
    for (int off = 1; off < 256; off <<= 1) {
        int t = (threadIdx.x >= (unsigned)off) ? buf[threadIdx.x - off] : 0;
        __syncthreads();
        buf[threadIdx.x] += t;
        __syncthreads();
    }
    if (idx < NNODES) rowptr[idx + 1] = buf[threadIdx.x];
    if (threadIdx.x == 255) bsums[blockIdx.x] = buf[255];
}

__global__ __launch_bounds__(128) void scan2_k(int* __restrict__ bsums) {
    __shared__ int buf[128];
    int v = (threadIdx.x < SCAN_BLOCKS) ? bsums[threadIdx.x] : 0;
    buf[threadIdx.x] = v;
    __syncthreads();
#pragma unroll
    for (int off = 1; off < 128; off <<= 1) {
        int t = (threadIdx.x >= (unsigned)off) ? buf[threadIdx.x - off] : 0;
        __syncthreads();
        buf[threadIdx.x] += t;
        __syncthreads();
    }
    if (threadIdx.x < SCAN_BLOCKS) bsums[threadIdx.x] = buf[threadIdx.x];
}

__global__ void scan3_k(int* __restrict__ rowptr, const int* __restrict__ bsums) {
    int idx = blockIdx.x * 256 + threadIdx.x;
    if (blockIdx.x > 0 && idx < NNODES) rowptr[idx + 1] += bsums[blockIdx.x - 1];
}

__global__ void copy_cursor_k(const int* __restrict__ rowptr, int* __restrict__ cursor) {
    int i = blockIdx.x * 256 + threadIdx.x;
    if (i < NNODES) cursor[i] = rowptr[i];
}

__global__ void scatter_k(const int* __restrict__ src, const int* __restrict__ dst,
                          int* __restrict__ cursor, int* __restrict__ colsrc) {
    int i = blockIdx.x * 256 + threadIdx.x;
    if (i < EEDGES) {
        int d = dst[i];
        int pos = atomicAdd(&cursor[d], 1);
        colsrc[pos] = src[i];
    }
}

// ---------------- W3 folding ----------------

__global__ void w3sum_k(const float* __restrict__ W3, float* __restrict__ wsum) {
    int i = blockIdx.x * 256 + threadIdx.x;
    if (i < DD * DD) wsum[i] = W3[i] + W3[i + DD * DD];
}

// ---------------- fp32 GEMM: C[M,256] = act(A)[M,256] @ B[256,256] ----------------
// 64x64 tile, 256 threads (4 waves), 4x4 micro-tile, double-buffered LDS with a
// single __syncthreads per K-slab; global prefetch overlaps the FMA block.

template<bool RELU_A>
__global__ __launch_bounds__(256) void gemm_k(const float* __restrict__ A,
                                              const float* __restrict__ B,
                                              float* __restrict__ C, int M) {
    __shared__ float As[2][16][68];   // transposed A slab, pad 68 -> 2-way max (free)
    __shared__ float Bs[2][16][64];
    const int t  = threadIdx.x;
    const int tx = t & 15;   // col group (4 cols)
    const int ty = t >> 4;   // row group (4 rows)
    const int rowBase = blockIdx.y * 64;
    const int colBase = blockIdx.x * 64;

    float acc[4][4];
#pragma unroll
    for (int i = 0; i < 4; ++i)
#pragma unroll
        for (int j = 0; j < 4; ++j) acc[i][j] = 0.f;

    const int ar = t >> 2;          // 0..63  A row in tile
    const int ac = (t & 3) * 4;     // 0..12  A k-offset
    const int br = t >> 4;          // 0..15  B k-row
    const int bc = (t & 15) * 4;    // 0..60  B col
    const int arow = rowBase + ar;

    float4 a0 = make_float4(0.f, 0.f, 0.f, 0.f);
    float4 b0;
    if (arow < M) a0 = *(const float4*)(A + (size_t)arow * DD + ac);
    b0 = *(const float4*)(B + (size_t)br * DD + colBase + bc);
    if (RELU_A) {
        a0.x = fmaxf(a0.x, 0.f); a0.y = fmaxf(a0.y, 0.f);
        a0.z = fmaxf(a0.z, 0.f); a0.w = fmaxf(a0.w, 0.f);
    }
    As[0][ac + 0][ar] = a0.x; As[0][ac + 1][ar] = a0.y;
    As[0][ac + 2][ar] = a0.z; As[0][ac + 3][ar] = a0.w;
    *(float4*)&Bs[0][br][bc] = b0;
    __syncthreads();

    for (int s = 0; s < 16; ++s) {
        const int cur = s & 1;
        const bool hasNext = (s < 15);
        if (hasNext) {
            int kn = (s + 1) * 16;
            if (arow < M) a0 = *(const float4*)(A + (size_t)arow * DD + kn + ac);
            b0 = *(const float4*)(B + (size_t)(kn + br) * DD + colBase + bc);
        }
#pragma unroll
        for (int kk = 0; kk < 16; ++kk) {
            float a[4], b[4];
            *(float4*)&a[0] = *(const float4*)&As[cur][kk][ty * 4];
            *(float4*)&b[0] = *(const float4*)&Bs[cur][kk][tx * 4];
#pragma unroll
            for (int i = 0; i < 4; ++i)
#pragma unroll
                for (int j = 0; j < 4; ++j)
                    acc[i][j] = fmaf(a[i], b[j], acc[i][j]);
        }
        if (hasNext) {
            if (RELU_A) {
                a0.x = fmaxf(a0.x, 0.f); a0.y = fmaxf(a0.y, 0.f);
                a0.z = fmaxf(a0.z, 0.f); a0.w = fmaxf(a0.w, 0.f);
            }
            const int nxt = 1 - cur;
            As[nxt][ac + 0][ar] = a0.x; As[nxt][ac + 1][ar] = a0.y;
            As[nxt][ac + 2][ar] = a0.z; As[nxt][ac + 3][ar] = a0.w;
            *(float4*)&Bs[nxt][br][bc] = b0;
            __syncthreads();
        }
    }

#pragma unroll
    for (int i = 0; i < 4; ++i) {
        int r = rowBase + ty * 4 + i;
        if (r < M) {
            float4 o = make_float4(acc[i][0], acc[i][1], acc[i][2], acc[i][3]);
            *(float4*)(C + (size_t)r * DD + colBase + tx * 4) = o;
        }
    }
}

// ---------------- per-node attention dots ----------------

__global__ __launch_bounds__(256) void dots_k(const float* __restrict__ hw,
                                              const float* __restrict__ asrc,
                                              const float* __restrict__ adst,
                                              float* __restrict__ es, float* __restrict__ ed) {
    int wave = threadIdx.x >> 6;
    int lane = threadIdx.x & 63;
    int node = blockIdx.x * 4 + wave;
    if (node >= NNODES) return;
    float4 v = *(const float4*)(hw + (size_t)node * DD + lane * 4);
    float4 a = *(const float4*)(asrc + lane * 4);
    float4 b = *(const float4*)(adst + lane * 4);
    float s = v.x * a.x + v.y * a.y + v.z * a.z + v.w * a.w;
    float d = v.x * b.x + v.y * b.y + v.z * b.z + v.w * b.w;
#pragma unroll
    for (int off = 32; off; off >>= 1) {
        s += __shfl_xor(s, off);
        d += __shfl_xor(d, off);
    }
    if (lane == 0) { es[node] = s; ed[node] = d; }
}

// ---------------- fused segment softmax + weighted aggregation ----------------
// one wave per node; deg<=64 fast path keeps everything in registers; phase C
// unrolled x8 (then x4, x1) for memory-level parallelism.

__global__ __launch_bounds__(256) void gat_agg_k(const float* __restrict__ hw,
                                                 const float* __restrict__ es,
                                                 const float* __restrict__ ed,
                                                 const int* __restrict__ rowptr,
                                                 const int* __restrict__ colsrc,
                                                 float* __restrict__ ealpha,
                                                 const float* __restrict__ bias,
                                                 float* __restrict__ hout) {
    int wave = threadIdx.x >> 6;
    int lane = threadIdx.x & 63;
    int node = blockIdx.x * 4 + wave;
    if (node >= NNODES) return;
    int start = rowptr[node], end = rowptr[node + 1];
    int deg = end - start;
    float edd = ed[node];

    float4 acc[8];
#pragma unroll
    for (int i = 0; i < 8; ++i) acc[i] = make_float4(0.f, 0.f, 0.f, 0.f);

    if (deg <= 64) {
        if (deg > 0) {
            int j = start + lane;
            bool valid = j < end;
            int msrc = valid ? colsrc[j] : 0;
            float e = valid ? es[msrc] + edd : -INFINITY;
            e = fmaxf(e, NEG_SLOPE * e);                  // leaky_relu
            float mx = e;
#pragma unroll
            for (int off = 32; off; off >>= 1) mx = fmaxf(mx, __shfl_xor(mx, off));
            float ee = valid ? expf(e - mx) : 0.f;
            float sum = ee;
#pragma unroll
            for (int off = 32; off; off >>= 1) sum += __shfl_xor(sum, off);
            float w = ee / sum;                            // this lane's alpha

            int j2 = 0;
            for (; j2 + 8 <= deg; j2 += 8) {
                int   sv[8]; float wv[8];
#pragma unroll
                for (int u = 0; u < 8; ++u) {
                    sv[u] = __shfl(msrc, j2 + u);
                    wv[u] = __shfl(w, j2 + u);
                }
                float4 vv[8];
#pragma unroll
                for (int u = 0; u < 8; ++u)
                    vv[u] = *(const float4*)(hw + (size_t)sv[u] * DD + lane * 4);
#pragma unroll
                for (int u = 0; u < 8; ++u) {
                    acc[u].x = fmaf(wv[u], vv[u].x, acc[u].x);
                    acc[u].y = fmaf(wv[u], vv[u].y, acc[u].y);
                    acc[u].z = fmaf(wv[u], vv[u].z, acc[u].z);
                    acc[u].w = fmaf(wv[u], vv[u].w, acc[u].w);
                }
            }
            if (j2 + 4 <= deg) {
                int   sv[4]; float wv[4];
#pragma unroll
                for (int u = 0; u < 4; ++u) {
                    sv[u] = __shfl(msrc, j2 + u);
                    wv[u] = __shfl(w, j2 + u);
                }
                float4 vv[4];
#pragma unroll
                for (int u = 0; u < 4; ++u)
                    vv[u] = *(const float4*)(hw + (size_t)sv[u] * DD + lane * 4);
#pragma unroll
                for (int u = 0; u < 4; ++u) {
                    acc[u].x = fmaf(wv[u], vv[u].x, acc[u].x);
                    acc[u].y = fmaf(wv[u], vv[u].y, acc[u].y);
                    acc[u].z = fmaf(wv[u], vv[u].z, acc[u].z);
                    acc[u].w = fmaf(wv[u], vv[u].w, acc[u].w);
                }
                j2 += 4;
            }
            for (; j2 < deg; ++j2) {
                int   s0 = __shfl(msrc, j2);
                float w0 = __shfl(w, j2);
                float4 v0 = *(const float4*)(hw + (size_t)s0 * DD + lane * 4);
                acc[j2 & 3].x = fmaf(w0, v0.x, acc[j2 & 3].x);
                acc[j2 & 3].y = fmaf(w0, v0.y, acc[j2 & 3].y);
                acc[j2 & 3].z = fmaf(w0, v0.z, acc[j2 & 3].z);
                acc[j2 & 3].w = fmaf(w0, v0.w, acc[j2 & 3].w);
            }
        }
    } else {
        // rare fallback: deg > 64, global scratch
        float mx = -INFINITY;
        for (int j = start + lane; j < end; j += 64) {
            float e = es[colsrc[j]] + edd;
            e = fmaxf(e, NEG_SLOPE * e);
            mx = fmaxf(mx, e);
        }
#pragma unroll
        for (int off = 32; off; off >>= 1) mx = fmaxf(mx, __shfl_xor(mx, off));
        float sum = 0.f;
        for (int j = start + lane; j < end; j += 64) {
            float e = es[colsrc[j]] + edd;
            e = fmaxf(e, NEG_SLOPE * e);
            float ee = expf(e - mx);
            ealpha[j] = ee;
            sum += ee;
        }
#pragma unroll
        for (int off = 32; off; off >>= 1) sum += __shfl_xor(sum, off);
        float inv = 1.f / sum;
        int j = start;
        for (; j + 4 <= end; j += 4) {
            int s0 = colsrc[j], s1 = colsrc[j + 1], s2 = colsrc[j + 2], s3 = colsrc[j + 3];
            float w0 = ealpha[j] * inv, w1 = ealpha[j + 1] * inv;
            float w2 = ealpha[j + 2] * inv, w3 = ealpha[j + 3] * inv;
            float4 v0 = *(const float4*)(hw + (size_t)s0 * DD + lane * 4);
            float4 v1 = *(const float4*)(hw + (size_t)s1 * DD + lane * 4);
            float4 v2 = *(const float4*)(hw + (size_t)s2 * DD + lane * 4);
            float4 v3 = *(const float4*)(hw + (size_t)s3 * DD + lane * 4);
            acc[0].x = fmaf(w0, v0.x, acc[0].x); acc[0].y = fmaf(w0, v0.y, acc[0].y);
            acc[0].z = fmaf(w0, v0.z, acc[0].z); acc[0].w = fmaf(w0, v0.w, acc[0].w);
            acc[1].x = fmaf(w1, v1.x, acc[1].x); acc[1].y = fmaf(w1, v1.y, acc[1].y);
            acc[1].z = fmaf(w1, v1.z, acc[1].z); acc[1].w = fmaf(w1, v1.w, acc[1].w);
            acc[2].x = fmaf(w2, v2.x, acc[2].x); acc[2].y = fmaf(w2, v2.y, acc[2].y);
            acc[2].z = fmaf(w2, v2.z, acc[2].z); acc[2].w = fmaf(w2, v2.w, acc[2].w);
            acc[3].x = fmaf(w3, v3.x, acc[3].x); acc[3].y = fmaf(w3, v3.y, acc[3].y);
            acc[3].z = fmaf(w3, v3.z, acc[3].z); acc[3].w = fmaf(w3, v3.w, acc[3].w);
        }
        for (; j < end; ++j) {
            int s0 = colsrc[j];
            float w0 = ealpha[j] * inv;
            float4 v0 = *(const float4*)(hw + (size_t)s0 * DD + lane * 4);
            acc[0].x = fmaf(w0, v0.x, acc[0].x); acc[0].y = fmaf(w0, v0.y, acc[0].y);
            acc[0].z = fmaf(w0, v0.z, acc[0].z); acc[0].w = fmaf(w0, v0.w, acc[0].w);
        }
    }

#pragma unroll
    for (int u = 4; u < 8; ++u) {
        acc[u - 4].x += acc[u].x; acc[u - 4].y += acc[u].y;
        acc[u - 4].z += acc[u].z; acc[u - 4].w += acc[u].w;
    }
    acc[0].x += acc[1].x; acc[0].y += acc[1].y; acc[0].z += acc[1].z; acc[0].w += acc[1].w;
    acc[2].x += acc[3].x; acc[2].y += acc[3].y; acc[2].z += acc[3].z; acc[2].w += acc[3].w;
    acc[0].x += acc[2].x; acc[0].y += acc[2].y; acc[0].z += acc[2].z; acc[0].w += acc[2].w;
    float4 b4 = *(const float4*)(bias + lane * 4);
    acc[0].x += b4.x; acc[0].y += b4.y; acc[0].z += b4.z; acc[0].w += b4.w;
    *(float4*)(hout + (size_t)node * DD + lane * 4) = acc[0];
}

// ---------------- driver ----------------

extern "C" void kernel_launch(void* const* d_in, const int* in_sizes, int n_in,
                              void* d_out, int out_size, void* d_ws, size_t ws_size,
                              hipStream_t stream) {
    const float* x     = (const float*)d_in[0];
    const int*   ei    = (const int*)d_in[1];     // [2,E]: first E = src, next E = dst
    const float* W1    = (const float*)d_in[2];
    const float* W2    = (const float*)d_in[3];
    const float* Ws    = (const float*)d_in[4];   // [6,256,256]
    const float* a_src = (const float*)d_in[5];   // [6,256]
    const float* a_dst = (const float*)d_in[6];
    const float* bias  = (const float*)d_in[7];   // [6,256]
    const float* W3    = (const float*)d_in[8];   // [512,256]
    float* out = (float*)d_out;

    const int* src = ei;
    const int* dst = ei + EEDGES;

    // workspace carve-up
    float* bufA   = (float*)d_ws;                      // N*D
    float* bufB   = bufA + (size_t)NNODES * DD;        // N*D
    float* es     = bufB + (size_t)NNODES * DD;        // N
    float* edv    = es + NNODES;                       // N
    float* ealpha = edv + NNODES;                      // E
    float* w3s    = ealpha + EEDGES;                   // 256*256
    int*   rowptr = (int*)(w3s + DD * DD);             // N+1
    int*   cursor = rowptr + (NNODES + 1);             // N
    int*   colsrc = cursor + NNODES;                   // E
    int*   bsums  = colsrc + EEDGES;                   // SCAN_BLOCKS

    // --- CSR build (per call; harness poisons ws) ---
    zero_ints_k<<<(NNODES + 1 + 255) / 256, 256, 0, stream>>>(rowptr, NNODES + 1);
    hist_k<<<(EEDGES + 255) / 256, 256, 0, stream>>>(dst, rowptr);
    scan1_k<<<SCAN_BLOCKS, 256, 0, stream>>>(rowptr, bsums);
    scan2_k<<<1, 128, 0, stream>>>(bsums);
    scan3_k<<<SCAN_BLOCKS, 256, 0, stream>>>(rowptr, bsums);
    copy_cursor_k<<<(NNODES + 255) / 256, 256, 0, stream>>>(rowptr, cursor);
    scatter_k<<<(EEDGES + 255) / 256, 256, 0, stream>>>(src, dst, cursor, colsrc);
    w3sum_k<<<(DD * DD + 255) / 256, 256, 0, stream>>>(W3, w3s);

    dim3 ggrid(DD / 64, (NNODES + 63) / 64);
    const int nodeBlocks = (NNODES + 3) / 4;

    // h = (x @ W1) @ W2
    gemm_k<false><<<ggrid, 256, 0, stream>>>(x, W1, bufA, NNODES);
    gemm_k<false><<<ggrid, 256, 0, stream>>>(bufA, W2, bufB, NNODES);

    // 6 GAT layers; cur lives in bufB, hw in bufA each layer
    for (int l = 0; l < 6; ++l) {
        gemm_k<false><<<ggrid, 256, 0, stream>>>(bufB, Ws + (size_t)l * DD * DD, bufA, NNODES);
        dots_k<<<nodeBlocks, 256, 0, stream>>>(bufA, a_src + (size_t)l * DD, a_dst + (size_t)l * DD, es, edv);
        gat_agg_k<<<nodeBlocks, 256, 0, stream>>>(bufA, es, edv, rowptr, colsrc, ealpha,
                                                  bias + (size_t)l * DD, bufB);
    }

    // out = relu(h) @ (W3_top + W3_bot)
    gemm_k<true><<<ggrid, 256, 0, stream>>>(bufB, w3s, out, NNODES);
}

// Round 6
// 1023.007 us; speedup vs baseline: 1.1542x; 1.1542x over previous
//
#include <hip/hip_runtime.h>

#define NNODES 20000
#define EEDGES 320000
#define DD     256
#define NEG_SLOPE 0.2f
#define SCAN_BLOCKS ((NNODES + 255) / 256)

// ---------------- CSR build ----------------

__global__ void zero_ints_k(int* __restrict__ p, int n) {
    int i = blockIdx.x * 256 + threadIdx.x;
    if (i < n) p[i] = 0;
}

__global__ void hist_k(const int* __restrict__ dst, int* __restrict__ rowptr) {
    int i = blockIdx.x * 256 + threadIdx.x;
    if (i < EEDGES) atomicAdd(&rowptr[dst[i] + 1], 1);
}

__global__ __launch_bounds__(256) void scan1_k(int* __restrict__ rowptr, int* __restrict__ bsums) {
    __shared__ int buf[256];
    int idx = blockIdx.x * 256 + threadIdx.x;
    int v = (idx < NNODES) ? rowptr[idx + 1] : 0;
    buf[threadIdx.x] = v;
    __syncthreads();
#pragma unroll
    for (int off = 1; off < 256; off <<= 1) {
        int t = (threadIdx.x >= (unsigned)off) ? buf[threadIdx.x - off] : 0;
        __syncthreads();
        buf[threadIdx.x] += t;
        __syncthreads();
    }
    if (idx < NNODES) rowptr[idx + 1] = buf[threadIdx.x];
    if (threadIdx.x == 255) bsums[blockIdx.x] = buf[255];
}

__global__ __launch_bounds__(128) void scan2_k(int* __restrict__ bsums) {
    __shared__ int buf[128];
    int v = (threadIdx.x < SCAN_BLOCKS) ? bsums[threadIdx.x] : 0;
    buf[threadIdx.x] = v;
    __syncthreads();
#pragma unroll
    for (int off = 1; off < 128; off <<= 1) {
        int t = (threadIdx.x >= (unsigned)off) ? buf[threadIdx.x - off] : 0;
        __syncthreads();
        buf[threadIdx.x] += t;
        __syncthreads();
    }
    if (threadIdx.x < SCAN_BLOCKS) bsums[threadIdx.x] = buf[threadIdx.x];
}

__global__ void scan3_k(int* __restrict__ rowptr, const int* __restrict__ bsums) {
    int idx = blockIdx.x * 256 + threadIdx.x;
    if (blockIdx.x > 0 && idx < NNODES) rowptr[idx + 1] += bsums[blockIdx.x - 1];
}

__global__ void copy_cursor_k(const int* __restrict__ rowptr, int* __restrict__ cursor) {
    int i = blockIdx.x * 256 + threadIdx.x;
    if (i < NNODES) cursor[i] = rowptr[i];
}

__global__ void scatter_k(const int* __restrict__ src, const int* __restrict__ dst,
                          int* __restrict__ cursor, int* __restrict__ colsrc) {
    int i = blockIdx.x * 256 + threadIdx.x;
    if (i < EEDGES) {
        int d = dst[i];
        int pos = atomicAdd(&cursor[d], 1);
        colsrc[pos] = src[i];
    }
}

// ---------------- W3 folding ----------------

__global__ void w3sum_k(const float* __restrict__ W3, float* __restrict__ wsum) {
    int i = blockIdx.x * 256 + threadIdx.x;
    if (i < DD * DD) wsum[i] = W3[i] + W3[i + DD * DD];
}

// ---------------- fp32 GEMM: C[M,256] = act(A)[M,256] @ B[256,256] ----------------
// 64 rows x 128 cols, 128 threads (2 waves), 8x8 micro-tile => 1.0 B LDS per FMA
// (the CU balance point). Double-buffered LDS, one barrier per K-slab.

template<bool RELU_A>
__global__ __launch_bounds__(128) void gemm_k(const float* __restrict__ A,
                                              const float* __restrict__ B,
                                              float* __restrict__ C, int M) {
    __shared__ float As[2][16][66];    // transposed A slab; pad 66 -> writes 2-way (free)
    __shared__ float Bs[2][16][128];
    const int t  = threadIdx.x;
    const int tx = t & 15;   // col group
    const int ty = t >> 4;   // row group (8 rows)
    const int rowBase = blockIdx.y * 64;
    const int colBase = blockIdx.x * 128;

    float acc[8][8];
#pragma unroll
    for (int i = 0; i < 8; ++i)
#pragma unroll
        for (int j = 0; j < 8; ++j) acc[i][j] = 0.f;

    const int ar = t >> 1;          // 0..63  A row in tile
    const int ac = (t & 1) * 8;     // 0 or 8 A k-offset
    const int br = t >> 5;          // 0..3   B k-row base
    const int bc = (t & 31) * 4;    // 0..124 B col
    const int arow = rowBase + ar;

    float4 a0 = make_float4(0.f, 0.f, 0.f, 0.f);
    float4 a1 = make_float4(0.f, 0.f, 0.f, 0.f);
    float4 b0, b1, b2, b3;
    if (arow < M) {
        a0 = *(const float4*)(A + (size_t)arow * DD + ac);
        a1 = *(const float4*)(A + (size_t)arow * DD + ac + 4);
    }
    b0 = *(const float4*)(B + (size_t)(br     ) * DD + colBase + bc);
    b1 = *(const float4*)(B + (size_t)(br +  4) * DD + colBase + bc);
    b2 = *(const float4*)(B + (size_t)(br +  8) * DD + colBase + bc);
    b3 = *(const float4*)(B + (size_t)(br + 12) * DD + colBase + bc);
    if (RELU_A) {
        a0.x = fmaxf(a0.x, 0.f); a0.y = fmaxf(a0.y, 0.f);
        a0.z = fmaxf(a0.z, 0.f); a0.w = fmaxf(a0.w, 0.f);
        a1.x = fmaxf(a1.x, 0.f); a1.y = fmaxf(a1.y, 0.f);
        a1.z = fmaxf(a1.z, 0.f); a1.w = fmaxf(a1.w, 0.f);
    }
    As[0][ac + 0][ar] = a0.x; As[0][ac + 1][ar] = a0.y;
    As[0][ac + 2][ar] = a0.z; As[0][ac + 3][ar] = a0.w;
    As[0][ac + 4][ar] = a1.x; As[0][ac + 5][ar] = a1.y;
    As[0][ac + 6][ar] = a1.z; As[0][ac + 7][ar] = a1.w;
    *(float4*)&Bs[0][br     ][bc] = b0;
    *(float4*)&Bs[0][br +  4][bc] = b1;
    *(float4*)&Bs[0][br +  8][bc] = b2;
    *(float4*)&Bs[0][br + 12][bc] = b3;
    __syncthreads();

    for (int s = 0; s < 16; ++s) {
        const int cur = s & 1;
        const bool hasNext = (s < 15);
        if (hasNext) {
            int kn = (s + 1) * 16;
            if (arow < M) {
                a0 = *(const float4*)(A + (size_t)arow * DD + kn + ac);
                a1 = *(const float4*)(A + (size_t)arow * DD + kn + ac + 4);
            }
            b0 = *(const float4*)(B + (size_t)(kn + br     ) * DD + colBase + bc);
            b1 = *(const float4*)(B + (size_t)(kn + br +  4) * DD + colBase + bc);
            b2 = *(const float4*)(B + (size_t)(kn + br +  8) * DD + colBase + bc);
            b3 = *(const float4*)(B + (size_t)(kn + br + 12) * DD + colBase + bc);
        }
#pragma unroll
        for (int kk = 0; kk < 16; ++kk) {
            float a[8], b[8];
            *(float4*)&a[0] = *(const float4*)&As[cur][kk][ty * 8];
            *(float4*)&a[4] = *(const float4*)&As[cur][kk][ty * 8 + 4];
            *(float4*)&b[0] = *(const float4*)&Bs[cur][kk][tx * 4];
            *(float4*)&b[4] = *(const float4*)&Bs[cur][kk][tx * 4 + 64];
#pragma unroll
            for (int i = 0; i < 8; ++i)
#pragma unroll
                for (int j = 0; j < 8; ++j)
                    acc[i][j] = fmaf(a[i], b[j], acc[i][j]);
        }
        if (hasNext) {
            if (RELU_A) {
                a0.x = fmaxf(a0.x, 0.f); a0.y = fmaxf(a0.y, 0.f);
                a0.z = fmaxf(a0.z, 0.f); a0.w = fmaxf(a0.w, 0.f);
                a1.x = fmaxf(a1.x, 0.f); a1.y = fmaxf(a1.y, 0.f);
                a1.z = fmaxf(a1.z, 0.f); a1.w = fmaxf(a1.w, 0.f);
            }
            const int nxt = 1 - cur;
            As[nxt][ac + 0][ar] = a0.x; As[nxt][ac + 1][ar] = a0.y;
            As[nxt][ac + 2][ar] = a0.z; As[nxt][ac + 3][ar] = a0.w;
            As[nxt][ac + 4][ar] = a1.x; As[nxt][ac + 5][ar] = a1.y;
            As[nxt][ac + 6][ar] = a1.z; As[nxt][ac + 7][ar] = a1.w;
            *(float4*)&Bs[nxt][br     ][bc] = b0;
            *(float4*)&Bs[nxt][br +  4][bc] = b1;
            *(float4*)&Bs[nxt][br +  8][bc] = b2;
            *(float4*)&Bs[nxt][br + 12][bc] = b3;
            __syncthreads();
        }
    }

#pragma unroll
    for (int i = 0; i < 8; ++i) {
        int r = rowBase + ty * 8 + i;
        if (r < M) {
            float4 o0 = make_float4(acc[i][0], acc[i][1], acc[i][2], acc[i][3]);
            float4 o1 = make_float4(acc[i][4], acc[i][5], acc[i][6], acc[i][7]);
            *(float4*)(C + (size_t)r * DD + colBase + tx * 4) = o0;
            *(float4*)(C + (size_t)r * DD + colBase + tx * 4 + 64) = o1;
        }
    }
}

// ---------------- per-node attention dots ----------------

__global__ __launch_bounds__(256) void dots_k(const float* __restrict__ hw,
                                              const float* __restrict__ asrc,
                                              const float* __restrict__ adst,
                                              float* __restrict__ es, float* __restrict__ ed) {
    int wave = threadIdx.x >> 6;
    int lane = threadIdx.x & 63;
    int node = blockIdx.x * 4 + wave;
    if (node >= NNODES) return;
    float4 v = *(const float4*)(hw + (size_t)node * DD + lane * 4);
    float4 a = *(const float4*)(asrc + lane * 4);
    float4 b = *(const float4*)(adst + lane * 4);
    float s = v.x * a.x + v.y * a.y + v.z * a.z + v.w * a.w;
    float d = v.x * b.x + v.y * b.y + v.z * b.z + v.w * b.w;
#pragma unroll
    for (int off = 32; off; off >>= 1) {
        s += __shfl_xor(s, off);
        d += __shfl_xor(d, off);
    }
    if (lane == 0) { es[node] = s; ed[node] = d; }
}

// ---------------- fused segment softmax + weighted aggregation ----------------
// one wave per node; deg<=64 path keeps scores in registers (alpha via shuffle);
// gather loop 8-wide into NAMED accumulators only — every register index is a
// compile-time constant (dynamic indexing demotes arrays to scratch: round-5 lesson).

__global__ __launch_bounds__(256) void gat_agg_k(const float* __restrict__ hw,
                                                 const float* __restrict__ es,
                                                 const float* __restrict__ ed,
                                                 const int* __restrict__ rowptr,
                                                 const int* __restrict__ colsrc,
                                                 float* __restrict__ ealpha,
                                                 const float* __restrict__ bias,
                                                 float* __restrict__ hout) {
    int wave = threadIdx.x >> 6;
    int lane = threadIdx.x & 63;
    int node = blockIdx.x * 4 + wave;
    if (node >= NNODES) return;
    int start = rowptr[node], end = rowptr[node + 1];
    int deg = end - start;
    float edd = ed[node];

    float4 acc0 = make_float4(0.f, 0.f, 0.f, 0.f);
    float4 acc1 = acc0, acc2 = acc0, acc3 = acc0;
    float4 acc4 = acc0, acc5 = acc0, acc6 = acc0, acc7 = acc0;

#define FMA4(ACC, W, V) \
    ACC.x = fmaf(W, V.x, ACC.x); ACC.y = fmaf(W, V.y, ACC.y); \
    ACC.z = fmaf(W, V.z, ACC.z); ACC.w = fmaf(W, V.w, ACC.w);

    if (deg <= 64) {
        if (deg > 0) {
            int j = start + lane;
            bool valid = j < end;
            int msrc = valid ? colsrc[j] : 0;
            float e = valid ? es[msrc] + edd : -INFINITY;
            e = fmaxf(e, NEG_SLOPE * e);                  // leaky_relu
            float mx = e;
#pragma unroll
            for (int off = 32; off; off >>= 1) mx = fmaxf(mx, __shfl_xor(mx, off));
            float ee = valid ? expf(e - mx) : 0.f;
            float sum = ee;
#pragma unroll
            for (int off = 32; off; off >>= 1) sum += __shfl_xor(sum, off);
            float w = ee / sum;                            // this lane's alpha

            int j2 = 0;
            for (; j2 + 8 <= deg; j2 += 8) {
                int s0 = __shfl(msrc, j2 + 0), s1 = __shfl(msrc, j2 + 1);
                int s2 = __shfl(msrc, j2 + 2), s3 = __shfl(msrc, j2 + 3);
                int s4 = __shfl(msrc, j2 + 4), s5 = __shfl(msrc, j2 + 5);
                int s6 = __shfl(msrc, j2 + 6), s7 = __shfl(msrc, j2 + 7);
                float w0 = __shfl(w, j2 + 0), w1 = __shfl(w, j2 + 1);
                float w2 = __shfl(w, j2 + 2), w3 = __shfl(w, j2 + 3);
                float w4 = __shfl(w, j2 + 4), w5 = __shfl(w, j2 + 5);
                float w6 = __shfl(w, j2 + 6), w7 = __shfl(w, j2 + 7);
                float4 v0 = *(const float4*)(hw + (size_t)s0 * DD + lane * 4);
                float4 v1 = *(const float4*)(hw + (size_t)s1 * DD + lane * 4);
                float4 v2 = *(const float4*)(hw + (size_t)s2 * DD + lane * 4);
                float4 v3 = *(const float4*)(hw + (size_t)s3 * DD + lane * 4);
                float4 v4 = *(const float4*)(hw + (size_t)s4 * DD + lane * 4);
                float4 v5 = *(const float4*)(hw + (size_t)s5 * DD + lane * 4);
                float4 v6 = *(const float4*)(hw + (size_t)s6 * DD + lane * 4);
                float4 v7 = *(const float4*)(hw + (size_t)s7 * DD + lane * 4);
                FMA4(acc0, w0, v0); FMA4(acc1, w1, v1);
                FMA4(acc2, w2, v2); FMA4(acc3, w3, v3);
                FMA4(acc4, w4, v4); FMA4(acc5, w5, v5);
                FMA4(acc6, w6, v6); FMA4(acc7, w7, v7);
            }
            if (j2 + 4 <= deg) {
                int s0 = __shfl(msrc, j2 + 0), s1 = __shfl(msrc, j2 + 1);
                int s2 = __shfl(msrc, j2 + 2), s3 = __shfl(msrc, j2 + 3);
                float w0 = __shfl(w, j2 + 0), w1 = __shfl(w, j2 + 1);
                float w2 = __shfl(w, j2 + 2), w3 = __shfl(w, j2 + 3);
                float4 v0 = *(const float4*)(hw + (size_t)s0 * DD + lane * 4);
                float4 v1 = *(const float4*)(hw + (size_t)s1 * DD + lane * 4);
                float4 v2 = *(const float4*)(hw + (size_t)s2 * DD + lane * 4);
                float4 v3 = *(const float4*)(hw + (size_t)s3 * DD + lane * 4);
                FMA4(acc0, w0, v0); FMA4(acc1, w1, v1);
                FMA4(acc2, w2, v2); FMA4(acc3, w3, v3);
                j2 += 4;
            }
            for (; j2 < deg; ++j2) {
                int   s0 = __shfl(msrc, j2);
                float w0 = __shfl(w, j2);
                float4 v0 = *(const float4*)(hw + (size_t)s0 * DD + lane * 4);
                FMA4(acc0, w0, v0);
            }
        }
    } else {
        // rare fallback: deg > 64, global scratch
        float mx = -INFINITY;
        for (int j = start + lane; j < end; j += 64) {
            float e = es[colsrc[j]] + edd;
            e = fmaxf(e, NEG_SLOPE * e);
            mx = fmaxf(mx, e);
        }
#pragma unroll
        for (int off = 32; off; off >>= 1) mx = fmaxf(mx, __shfl_xor(mx, off));
        float sum = 0.f;
        for (int j = start + lane; j < end; j += 64) {
            float e = es[colsrc[j]] + edd;
            e = fmaxf(e, NEG_SLOPE * e);
            float ee = expf(e - mx);
            ealpha[j] = ee;
            sum += ee;
        }
#pragma unroll
        for (int off = 32; off; off >>= 1) sum += __shfl_xor(sum, off);
        float inv = 1.f / sum;
        int j = start;
        for (; j + 4 <= end; j += 4) {
            int s0 = colsrc[j], s1 = colsrc[j + 1], s2 = colsrc[j + 2], s3 = colsrc[j + 3];
            float w0 = ealpha[j] * inv, w1 = ealpha[j + 1] * inv;
            float w2 = ealpha[j + 2] * inv, w3 = ealpha[j + 3] * inv;
            float4 v0 = *(const float4*)(hw + (size_t)s0 * DD + lane * 4);
            float4 v1 = *(const float4*)(hw + (size_t)s1 * DD + lane * 4);
            float4 v2 = *(const float4*)(hw + (size_t)s2 * DD + lane * 4);
            float4 v3 = *(const float4*)(hw + (size_t)s3 * DD + lane * 4);
            FMA4(acc0, w0, v0); FMA4(acc1, w1, v1);
            FMA4(acc2, w2, v2); FMA4(acc3, w3, v3);
        }
        for (; j < end; ++j) {
            int s0 = colsrc[j];
            float w0 = ealpha[j] * inv;
            float4 v0 = *(const float4*)(hw + (size_t)s0 * DD + lane * 4);
            FMA4(acc0, w0, v0);
        }
    }
#undef FMA4

    acc0.x += acc4.x; acc0.y += acc4.y; acc0.z += acc4.z; acc0.w += acc4.w;
    acc1.x += acc5.x; acc1.y += acc5.y; acc1.z += acc5.z; acc1.w += acc5.w;
    acc2.x += acc6.x; acc2.y += acc6.y; acc2.z += acc6.z; acc2.w += acc6.w;
    acc3.x += acc7.x; acc3.y += acc7.y; acc3.z += acc7.z; acc3.w += acc7.w;
    acc0.x += acc1.x; acc0.y += acc1.y; acc0.z += acc1.z; acc0.w += acc1.w;
    acc2.x += acc3.x; acc2.y += acc3.y; acc2.z += acc3.z; acc2.w += acc3.w;
    acc0.x += acc2.x; acc0.y += acc2.y; acc0.z += acc2.z; acc0.w += acc2.w;
    float4 b4 = *(const float4*)(bias + lane * 4);
    acc0.x += b4.x; acc0.y += b4.y; acc0.z += b4.z; acc0.w += b4.w;
    *(float4*)(hout + (size_t)node * DD + lane * 4) = acc0;
}

// ---------------- driver ----------------

extern "C" void kernel_launch(void* const* d_in, const int* in_sizes, int n_in,
                              void* d_out, int out_size, void* d_ws, size_t ws_size,
                              hipStream_t stream) {
    const float* x     = (const float*)d_in[0];
    const int*   ei    = (const int*)d_in[1];     // [2,E]: first E = src, next E = dst
    const float* W1    = (const float*)d_in[2];
    const float* W2    = (const float*)d_in[3];
    const float* Ws    = (const float*)d_in[4];   // [6,256,256]
    const float* a_src = (const float*)d_in[5];   // [6,256]
    const float* a_dst = (const float*)d_in[6];
    const float* bias  = (const float*)d_in[7];   // [6,256]
    const float* W3    = (const float*)d_in[8];   // [512,256]
    float* out = (float*)d_out;

    const int* src = ei;
    const int* dst = ei + EEDGES;

    // workspace carve-up
    float* bufA   = (float*)d_ws;                      // N*D
    float* bufB   = bufA + (size_t)NNODES * DD;        // N*D
    float* es     = bufB + (size_t)NNODES * DD;        // N
    float* edv    = es + NNODES;                       // N
    float* ealpha = edv + NNODES;                      // E
    float* w3s    = ealpha + EEDGES;                   // 256*256
    int*   rowptr = (int*)(w3s + DD * DD);             // N+1
    int*   cursor = rowptr + (NNODES + 1);             // N
    int*   colsrc = cursor + NNODES;                   // E
    int*   bsums  = colsrc + EEDGES;                   // SCAN_BLOCKS

    // --- CSR build (per call; harness poisons ws) ---
    zero_ints_k<<<(NNODES + 1 + 255) / 256, 256, 0, stream>>>(rowptr, NNODES + 1);
    hist_k<<<(EEDGES + 255) / 256, 256, 0, stream>>>(dst, rowptr);
    scan1_k<<<SCAN_BLOCKS, 256, 0, stream>>>(rowptr, bsums);
    scan2_k<<<1, 128, 0, stream>>>(bsums);
    scan3_k<<<SCAN_BLOCKS, 256, 0, stream>>>(rowptr, bsums);
    copy_cursor_k<<<(NNODES + 255) / 256, 256, 0, stream>>>(rowptr, cursor);
    scatter_k<<<(EEDGES + 255) / 256, 256, 0, stream>>>(src, dst, cursor, colsrc);
    w3sum_k<<<(DD * DD + 255) / 256, 256, 0, stream>>>(W3, w3s);

    dim3 ggrid(DD / 128, (NNODES + 63) / 64);
    const int nodeBlocks = (NNODES + 3) / 4;

    // h = (x @ W1) @ W2
    gemm_k<false><<<ggrid, 128, 0, stream>>>(x, W1, bufA, NNODES);
    gemm_k<false><<<ggrid, 128, 0, stream>>>(bufA, W2, bufB, NNODES);

    // 6 GAT layers; cur lives in bufB, hw in bufA each layer
    for (int l = 0; l < 6; ++l) {
        gemm_k<false><<<ggrid, 128, 0, stream>>>(bufB, Ws + (size_t)l * DD * DD, bufA, NNODES);
        dots_k<<<nodeBlocks, 256, 0, stream>>>(bufA, a_src + (size_t)l * DD, a_dst + (size_t)l * DD, es, edv);
        gat_agg_k<<<nodeBlocks, 256, 0, stream>>>(bufA, es, edv, rowptr, colsrc, ealpha,
                                                  bias + (size_t)l * DD, bufB);
    }

    // out = relu(h) @ (W3_top + W3_bot)
    gemm_k<true><<<ggrid, 128, 0, stream>>>(bufB, w3s, out, NNODES);
}

// Round 7
// 845.179 us; speedup vs baseline: 1.3970x; 1.2104x over previous
//
#include <hip/hip_runtime.h>

#define NNODES 20000
#define EEDGES 320000
#define DD     256
#define NEG_SLOPE 0.2f
#define SCAN_BLOCKS ((NNODES + 255) / 256)

// ---------------- CSR build ----------------

__global__ void zero_ints_k(int* __restrict__ p, int n) {
    int i = blockIdx.x * 256 + threadIdx.x;
    if (i < n) p[i] = 0;
}

__global__ void hist_k(const int* __restrict__ dst, int* __restrict__ rowptr) {
    int i = blockIdx.x * 256 + threadIdx.x;
    if (i < EEDGES) atomicAdd(&rowptr[dst[i] + 1], 1);
}

__global__ __launch_bounds__(256) void scan1_k(int* __restrict__ rowptr, int* __restrict__ bsums) {
    __shared__ int buf[256];
    int idx = blockIdx.x * 256 + threadIdx.x;
    int v = (idx < NNODES) ? rowptr[idx + 1] : 0;
    buf[threadIdx.x] = v;
    __syncthreads();
#pragma unroll
    for (int off = 1; off < 256; off <<= 1) {
        int t = (threadIdx.x >= (unsigned)off) ? buf[threadIdx.x - off] : 0;
        __syncthreads();
        buf[threadIdx.x] += t;
        __syncthreads();
    }
    if (idx < NNODES) rowptr[idx + 1] = buf[threadIdx.x];
    if (threadIdx.x == 255) bsums[blockIdx.x] = buf[255];
}

__global__ __launch_bounds__(128) void scan2_k(int* __restrict__ bsums) {
    __shared__ int buf[128];
    int v = (threadIdx.x < SCAN_BLOCKS) ? bsums[threadIdx.x] : 0;
    buf[threadIdx.x] = v;
    __syncthreads();
#pragma unroll
    for (int off = 1; off < 128; off <<= 1) {
        int t = (threadIdx.x >= (unsigned)off) ? buf[threadIdx.x - off] : 0;
        __syncthreads();
        buf[threadIdx.x] += t;
        __syncthreads();
    }
    if (threadIdx.x < SCAN_BLOCKS) bsums[threadIdx.x] = buf[threadIdx.x];
}

__global__ void scan3_k(int* __restrict__ rowptr, const int* __restrict__ bsums) {
    int idx = blockIdx.x * 256 + threadIdx.x;
    if (blockIdx.x > 0 && idx < NNODES) rowptr[idx + 1] += bsums[blockIdx.x - 1];
}

__global__ void copy_cursor_k(const int* __restrict__ rowptr, int* __restrict__ cursor) {
    int i = blockIdx.x * 256 + threadIdx.x;
    if (i < NNODES) cursor[i] = rowptr[i];
}

__global__ void scatter_k(const int* __restrict__ src, const int* __restrict__ dst,
                          int* __restrict__ cursor, int* __restrict__ colsrc) {
    int i = blockIdx.x * 256 + threadIdx.x;
    if (i < EEDGES) {
        int d = dst[i];
        int pos = atomicAdd(&cursor[d], 1);
        colsrc[pos] = src[i];
    }
}

// ---------------- W3 folding ----------------

__global__ void w3sum_k(const float* __restrict__ W3, float* __restrict__ wsum) {
    int i = blockIdx.x * 256 + threadIdx.x;
    if (i < DD * DD) wsum[i] = W3[i] + W3[i + DD * DD];
}

// ---------------- final output add: out = a + b ----------------

__global__ void add4_k(const float* __restrict__ a, const float* __restrict__ b,
                       float* __restrict__ o) {
    int i = blockIdx.x * 256 + threadIdx.x;   // float4 index
    if (i < NNODES * DD / 4) {
        float4 x = ((const float4*)a)[i];
        float4 y = ((const float4*)b)[i];
        x.x += y.x; x.y += y.y; x.z += y.z; x.w += y.w;
        ((float4*)o)[i] = x;
    }
}

// ---------------- fp32 GEMM, split-K x2 ----------------
// C_half[M,256] = act(A [+A2]) [M, k:k+128] @ B[k:k+128, 256]
// 64x64 tile, 128 threads, 8x4 micro (proven R4 structure: 45.4us full-K).
// blockIdx.z selects K-half and output buffer. Split-K doubles resident waves
// (2.4 -> 4.9 waves/SIMD) to hide barrier+load latency; reduction is fused
// into consumers (dots2_k / SUM_A input path / add4_k).

template<bool RELU_A, bool SUM_A>
__global__ __launch_bounds__(128, 4) void gemm_k(const float* __restrict__ A,
                                                 const float* __restrict__ A2,
                                                 const float* __restrict__ B,
                                                 float* __restrict__ C0,
                                                 float* __restrict__ C1, int M) {
    __shared__ float As[16][68];   // transposed, padded: writes 2-way max (free)
    __shared__ float Bs[16][64];
    const int t  = threadIdx.x;
    const int tx = t & 15;   // col group (4 cols)
    const int ty = t >> 4;   // row group (8 rows)
    const int rowBase = blockIdx.y * 64;
    const int colBase = blockIdx.x * 64;
    const int kbeg = blockIdx.z * 128;
    float* __restrict__ C = blockIdx.z ? C1 : C0;

    float acc[8][4];
#pragma unroll
    for (int i = 0; i < 8; ++i)
#pragma unroll
        for (int j = 0; j < 4; ++j) acc[i][j] = 0.f;

    const int ar = t >> 1;          // 0..63  A row in tile
    const int ac = (t & 1) * 8;     // 0 or 8 A k-offset
    const int br = t >> 4;          // 0..7   B k-row
    const int bc = (t & 15) * 4;    // 0..60  B col
    const int arow = rowBase + ar;

    float4 a0 = make_float4(0.f, 0.f, 0.f, 0.f);
    float4 a1 = make_float4(0.f, 0.f, 0.f, 0.f);
    float4 b0, b1;
    if (arow < M) {
        a0 = *(const float4*)(A + (size_t)arow * DD + kbeg + ac);
        a1 = *(const float4*)(A + (size_t)arow * DD + kbeg + ac + 4);
        if (SUM_A) {
            float4 x0 = *(const float4*)(A2 + (size_t)arow * DD + kbeg + ac);
            float4 x1 = *(const float4*)(A2 + (size_t)arow * DD + kbeg + ac + 4);
            a0.x += x0.x; a0.y += x0.y; a0.z += x0.z; a0.w += x0.w;
            a1.x += x1.x; a1.y += x1.y; a1.z += x1.z; a1.w += x1.w;
        }
    }
    b0 = *(const float4*)(B + (size_t)(kbeg + br    ) * DD + colBase + bc);
    b1 = *(const float4*)(B + (size_t)(kbeg + br + 8) * DD + colBase + bc);

    for (int s = 0; s < 8; ++s) {
        if (RELU_A) {
            a0.x = fmaxf(a0.x, 0.f); a0.y = fmaxf(a0.y, 0.f);
            a0.z = fmaxf(a0.z, 0.f); a0.w = fmaxf(a0.w, 0.f);
            a1.x = fmaxf(a1.x, 0.f); a1.y = fmaxf(a1.y, 0.f);
            a1.z = fmaxf(a1.z, 0.f); a1.w = fmaxf(a1.w, 0.f);
        }
        __syncthreads();
        As[ac + 0][ar] = a0.x; As[ac + 1][ar] = a0.y;
        As[ac + 2][ar] = a0.z; As[ac + 3][ar] = a0.w;
        As[ac + 4][ar] = a1.x; As[ac + 5][ar] = a1.y;
        As[ac + 6][ar] = a1.z; As[ac + 7][ar] = a1.w;
        *(float4*)&Bs[br    ][bc] = b0;
        *(float4*)&Bs[br + 8][bc] = b1;
        __syncthreads();

        if (s < 7) {
            int kn = kbeg + (s + 1) * 16;
            if (arow < M) {
                a0 = *(const float4*)(A + (size_t)arow * DD + kn + ac);
                a1 = *(const float4*)(A + (size_t)arow * DD + kn + ac + 4);
                if (SUM_A) {
                    float4 x0 = *(const float4*)(A2 + (size_t)arow * DD + kn + ac);
                    float4 x1 = *(const float4*)(A2 + (size_t)arow * DD + kn + ac + 4);
                    a0.x += x0.x; a0.y += x0.y; a0.z += x0.z; a0.w += x0.w;
                    a1.x += x1.x; a1.y += x1.y; a1.z += x1.z; a1.w += x1.w;
                }
            }
            b0 = *(const float4*)(B + (size_t)(kn + br    ) * DD + colBase + bc);
            b1 = *(const float4*)(B + (size_t)(kn + br + 8) * DD + colBase + bc);
        }

#pragma unroll
        for (int kk = 0; kk < 16; ++kk) {
            float a[8], b[4];
            *(float4*)&a[0] = *(const float4*)&As[kk][ty * 8];
            *(float4*)&a[4] = *(const float4*)&As[kk][ty * 8 + 4];
            *(float4*)&b[0] = *(const float4*)&Bs[kk][tx * 4];
#pragma unroll
            for (int i = 0; i < 8; ++i)
#pragma unroll
                for (int j = 0; j < 4; ++j)
                    acc[i][j] = fmaf(a[i], b[j], acc[i][j]);
        }
    }

#pragma unroll
    for (int i = 0; i < 8; ++i) {
        int r = rowBase + ty * 8 + i;
        if (r < M) {
            float4 o = make_float4(acc[i][0], acc[i][1], acc[i][2], acc[i][3]);
            *(float4*)(C + (size_t)r * DD + colBase + tx * 4) = o;
        }
    }
}

// ---------------- split-K merge + attention dots (fused) ----------------
// hw = hw0 + hw1 (materialized for the gather in gat_agg), es/ed = hw @ a_src/a_dst

__global__ __launch_bounds__(256) void dots2_k(const float* __restrict__ hw0,
                                               const float* __restrict__ hw1,
                                               const float* __restrict__ asrc,
                                               const float* __restrict__ adst,
                                               float* __restrict__ hw,
                                               float* __restrict__ es, float* __restrict__ ed) {
    int wave = threadIdx.x >> 6;
    int lane = threadIdx.x & 63;
    int node = blockIdx.x * 4 + wave;
    if (node >= NNODES) return;
    float4 v0 = *(const float4*)(hw0 + (size_t)node * DD + lane * 4);
    float4 v1 = *(const float4*)(hw1 + (size_t)node * DD + lane * 4);
    v0.x += v1.x; v0.y += v1.y; v0.z += v1.z; v0.w += v1.w;
    *(float4*)(hw + (size_t)node * DD + lane * 4) = v0;
    float4 a = *(const float4*)(asrc + lane * 4);
    float4 b = *(const float4*)(adst + lane * 4);
    float s = v0.x * a.x + v0.y * a.y + v0.z * a.z + v0.w * a.w;
    float d = v0.x * b.x + v0.y * b.y + v0.z * b.z + v0.w * b.w;
#pragma unroll
    for (int off = 32; off; off >>= 1) {
        s += __shfl_xor(s, off);
        d += __shfl_xor(d, off);
    }
    if (lane == 0) { es[node] = s; ed[node] = d; }
}

// ---------------- fused segment softmax + weighted aggregation ----------------
// one wave per node; deg<=64 path keeps scores in registers (alpha via shuffle);
// gather 8-wide into NAMED accumulators (compile-time register indices only).

__global__ __launch_bounds__(256) void gat_agg_k(const float* __restrict__ hw,
                                                 const float* __restrict__ es,
                                                 const float* __restrict__ ed,
                                                 const int* __restrict__ rowptr,
                                                 const int* __restrict__ colsrc,
                                                 float* __restrict__ ealpha,
                                                 const float* __restrict__ bias,
                                                 float* __restrict__ hout) {
    int wave = threadIdx.x >> 6;
    int lane = threadIdx.x & 63;
    int node = blockIdx.x * 4 + wave;
    if (node >= NNODES) return;
    int start = rowptr[node], end = rowptr[node + 1];
    int deg = end - start;
    float edd = ed[node];

    float4 acc0 = make_float4(0.f, 0.f, 0.f, 0.f);
    float4 acc1 = acc0, acc2 = acc0, acc3 = acc0;
    float4 acc4 = acc0, acc5 = acc0, acc6 = acc0, acc7 = acc0;

#define FMA4(ACC, W, V) \
    ACC.x = fmaf(W, V.x, ACC.x); ACC.y = fmaf(W, V.y, ACC.y); \
    ACC.z = fmaf(W, V.z, ACC.z); ACC.w = fmaf(W, V.w, ACC.w);

    if (deg <= 64) {
        if (deg > 0) {
            int j = start + lane;
            bool valid = j < end;
            int msrc = valid ? colsrc[j] : 0;
            float e = valid ? es[msrc] + edd : -INFINITY;
            e = fmaxf(e, NEG_SLOPE * e);                  // leaky_relu
            float mx = e;
#pragma unroll
            for (int off = 32; off; off >>= 1) mx = fmaxf(mx, __shfl_xor(mx, off));
            float ee = valid ? expf(e - mx) : 0.f;
            float sum = ee;
#pragma unroll
            for (int off = 32; off; off >>= 1) sum += __shfl_xor(sum, off);
            float w = ee / sum;                            // this lane's alpha

            int j2 = 0;
            for (; j2 + 8 <= deg; j2 += 8) {
                int s0 = __shfl(msrc, j2 + 0), s1 = __shfl(msrc, j2 + 1);
                int s2 = __shfl(msrc, j2 + 2), s3 = __shfl(msrc, j2 + 3);
                int s4 = __shfl(msrc, j2 + 4), s5 = __shfl(msrc, j2 + 5);
                int s6 = __shfl(msrc, j2 + 6), s7 = __shfl(msrc, j2 + 7);
                float w0 = __shfl(w, j2 + 0), w1 = __shfl(w, j2 + 1);
                float w2 = __shfl(w, j2 + 2), w3 = __shfl(w, j2 + 3);
                float w4 = __shfl(w, j2 + 4), w5 = __shfl(w, j2 + 5);
                float w6 = __shfl(w, j2 + 6), w7 = __shfl(w, j2 + 7);
                float4 v0 = *(const float4*)(hw + (size_t)s0 * DD + lane * 4);
                float4 v1 = *(const float4*)(hw + (size_t)s1 * DD + lane * 4);
                float4 v2 = *(const float4*)(hw + (size_t)s2 * DD + lane * 4);
                float4 v3 = *(const float4*)(hw + (size_t)s3 * DD + lane * 4);
                float4 v4 = *(const float4*)(hw + (size_t)s4 * DD + lane * 4);
                float4 v5 = *(const float4*)(hw + (size_t)s5 * DD + lane * 4);
                float4 v6 = *(const float4*)(hw + (size_t)s6 * DD + lane * 4);
                float4 v7 = *(const float4*)(hw + (size_t)s7 * DD + lane * 4);
                FMA4(acc0, w0, v0); FMA4(acc1, w1, v1);
                FMA4(acc2, w2, v2); FMA4(acc3, w3, v3);
                FMA4(acc4, w4, v4); FMA4(acc5, w5, v5);
                FMA4(acc6, w6, v6); FMA4(acc7, w7, v7);
            }
            if (j2 + 4 <= deg) {
                int s0 = __shfl(msrc, j2 + 0), s1 = __shfl(msrc, j2 + 1);
                int s2 = __shfl(msrc, j2 + 2), s3 = __shfl(msrc, j2 + 3);
                float w0 = __shfl(w, j2 + 0), w1 = __shfl(w, j2 + 1);
                float w2 = __shfl(w, j2 + 2), w3 = __shfl(w, j2 + 3);
                float4 v0 = *(const float4*)(hw + (size_t)s0 * DD + lane * 4);
                float4 v1 = *(const float4*)(hw + (size_t)s1 * DD + lane * 4);
                float4 v2 = *(const float4*)(hw + (size_t)s2 * DD + lane * 4);
                float4 v3 = *(const float4*)(hw + (size_t)s3 * DD + lane * 4);
                FMA4(acc0, w0, v0); FMA4(acc1, w1, v1);
                FMA4(acc2, w2, v2); FMA4(acc3, w3, v3);
                j2 += 4;
            }
            for (; j2 < deg; ++j2) {
                int   s0 = __shfl(msrc, j2);
                float w0 = __shfl(w, j2);
                float4 v0 = *(const float4*)(hw + (size_t)s0 * DD + lane * 4);
                FMA4(acc0, w0, v0);
            }
        }
    } else {
        // rare fallback: deg > 64, global scratch
        float mx = -INFINITY;
        for (int j = start + lane; j < end; j += 64) {
            float e = es[colsrc[j]] + edd;
            e = fmaxf(e, NEG_SLOPE * e);
            mx = fmaxf(mx, e);
        }
#pragma unroll
        for (int off = 32; off; off >>= 1) mx = fmaxf(mx, __shfl_xor(mx, off));
        float sum = 0.f;
        for (int j = start + lane; j < end; j += 64) {
            float e = es[colsrc[j]] + edd;
            e = fmaxf(e, NEG_SLOPE * e);
            float ee = expf(e - mx);
            ealpha[j] = ee;
            sum += ee;
        }
#pragma unroll
        for (int off = 32; off; off >>= 1) sum += __shfl_xor(sum, off);
        float inv = 1.f / sum;
        int j = start;
        for (; j + 4 <= end; j += 4) {
            int s0 = colsrc[j], s1 = colsrc[j + 1], s2 = colsrc[j + 2], s3 = colsrc[j + 3];
            float w0 = ealpha[j] * inv, w1 = ealpha[j + 1] * inv;
            float w2 = ealpha[j + 2] * inv, w3 = ealpha[j + 3] * inv;
            float4 v0 = *(const float4*)(hw + (size_t)s0 * DD + lane * 4);
            float4 v1 = *(const float4*)(hw + (size_t)s1 * DD + lane * 4);
            float4 v2 = *(const float4*)(hw + (size_t)s2 * DD + lane * 4);
            float4 v3 = *(const float4*)(hw + (size_t)s3 * DD + lane * 4);
            FMA4(acc0, w0, v0); FMA4(acc1, w1, v1);
            FMA4(acc2, w2, v2); FMA4(acc3, w3, v3);
        }
        for (; j < end; ++j) {
            int s0 = colsrc[j];
            float w0 = ealpha[j] * inv;
            float4 v0 = *(const float4*)(hw + (size_t)s0 * DD + lane * 4);
            FMA4(acc0, w0, v0);
        }
    }
#undef FMA4

    acc0.x += acc4.x; acc0.y += acc4.y; acc0.z += acc4.z; acc0.w += acc4.w;
    acc1.x += acc5.x; acc1.y += acc5.y; acc1.z += acc5.z; acc1.w += acc5.w;
    acc2.x += acc6.x; acc2.y += acc6.y; acc2.z += acc6.z; acc2.w += acc6.w;
    acc3.x += acc7.x; acc3.y += acc7.y; acc3.z += acc7.z; acc3.w += acc7.w;
    acc0.x += acc1.x; acc0.y += acc1.y; acc0.z += acc1.z; acc0.w += acc1.w;
    acc2.x += acc3.x; acc2.y += acc3.y; acc2.z += acc3.z; acc2.w += acc3.w;
    acc0.x += acc2.x; acc0.y += acc2.y; acc0.z += acc2.z; acc0.w += acc2.w;
    float4 b4 = *(const float4*)(bias + lane * 4);
    acc0.x += b4.x; acc0.y += b4.y; acc0.z += b4.z; acc0.w += b4.w;
    *(float4*)(hout + (size_t)node * DD + lane * 4) = acc0;
}

// ---------------- driver ----------------

extern "C" void kernel_launch(void* const* d_in, const int* in_sizes, int n_in,
                              void* d_out, int out_size, void* d_ws, size_t ws_size,
                              hipStream_t stream) {
    const float* x     = (const float*)d_in[0];
    const int*   ei    = (const int*)d_in[1];     // [2,E]: first E = src, next E = dst
    const float* W1    = (const float*)d_in[2];
    const float* W2    = (const float*)d_in[3];
    const float* Ws    = (const float*)d_in[4];   // [6,256,256]
    const float* a_src = (const float*)d_in[5];   // [6,256]
    const float* a_dst = (const float*)d_in[6];
    const float* bias  = (const float*)d_in[7];   // [6,256]
    const float* W3    = (const float*)d_in[8];   // [512,256]
    float* out = (float*)d_out;

    const int* src = ei;
    const int* dst = ei + EEDGES;

    // workspace carve-up (ws is ~248 MB; this uses ~130 MB)
    const size_t ND = (size_t)NNODES * DD;
    float* S0     = (float*)d_ws;          // N*D   split-K half 0
    float* S1     = S0 + ND;               // N*D   split-K half 1
    float* S2     = S1 + ND;               // N*D
    float* S3     = S2 + ND;               // N*D
    float* bufA   = S3 + ND;               // N*D   hw (merged)
    float* bufB   = bufA + ND;             // N*D   layer state
    float* es     = bufB + ND;             // N
    float* edv    = es + NNODES;           // N
    float* ealpha = edv + NNODES;          // E
    float* w3s    = ealpha + EEDGES;       // 256*256
    int*   rowptr = (int*)(w3s + DD * DD); // N+1
    int*   cursor = rowptr + (NNODES + 1); // N
    int*   colsrc = cursor + NNODES;       // E
    int*   bsums  = colsrc + EEDGES;       // SCAN_BLOCKS

    // --- CSR build (per call; harness poisons ws) ---
    zero_ints_k<<<(NNODES + 1 + 255) / 256, 256, 0, stream>>>(rowptr, NNODES + 1);
    hist_k<<<(EEDGES + 255) / 256, 256, 0, stream>>>(dst, rowptr);
    scan1_k<<<SCAN_BLOCKS, 256, 0, stream>>>(rowptr, bsums);
    scan2_k<<<1, 128, 0, stream>>>(bsums);
    scan3_k<<<SCAN_BLOCKS, 256, 0, stream>>>(rowptr, bsums);
    copy_cursor_k<<<(NNODES + 255) / 256, 256, 0, stream>>>(rowptr, cursor);
    scatter_k<<<(EEDGES + 255) / 256, 256, 0, stream>>>(src, dst, cursor, colsrc);
    w3sum_k<<<(DD * DD + 255) / 256, 256, 0, stream>>>(W3, w3s);

    dim3 ggrid(DD / 64, (NNODES + 63) / 64, 2);   // split-K x2
    const int nodeBlocks = (NNODES + 3) / 4;

    // t = x @ W1 (split halves S0,S1); u = t @ W2 (split halves S2,S3)
    gemm_k<false, false><<<ggrid, 128, 0, stream>>>(x, nullptr, W1, S0, S1, NNODES);
    gemm_k<false, true ><<<ggrid, 128, 0, stream>>>(S0, S1, W2, S2, S3, NNODES);

    // 6 GAT layers
    for (int l = 0; l < 6; ++l) {
        if (l == 0)
            gemm_k<false, true ><<<ggrid, 128, 0, stream>>>(S2, S3, Ws, S0, S1, NNODES);
        else
            gemm_k<false, false><<<ggrid, 128, 0, stream>>>(bufB, nullptr,
                                                            Ws + (size_t)l * DD * DD, S0, S1, NNODES);
        dots2_k<<<nodeBlocks, 256, 0, stream>>>(S0, S1, a_src + (size_t)l * DD,
                                                a_dst + (size_t)l * DD, bufA, es, edv);
        gat_agg_k<<<nodeBlocks, 256, 0, stream>>>(bufA, es, edv, rowptr, colsrc, ealpha,
                                                  bias + (size_t)l * DD, bufB);
    }

    // out = relu(h) @ (W3_top + W3_bot): split halves then add
    gemm_k<true, false><<<ggrid, 128, 0, stream>>>(bufB, nullptr, w3s, S2, S3, NNODES);
    add4_k<<<(NNODES * DD / 4 + 255) / 256, 256, 0, stream>>>(S2, S3, out);
}